// Round 1
// baseline (804.382 us; speedup 1.0000x reference)
//
#include <hip/hip_runtime.h>
#include <hip/hip_bf16.h>

#define NN 300
#define TB 16
#define TT 64          // t-tile per block
#define TTOT 4096
#define BNT ((size_t)TB * NN * TTOT)

// ---------------- prep: build W_e and per-row scalars ----------------
__global__ __launch_bounds__(64) void lic_prep_kernel(
    const float* __restrict__ sc, const float* __restrict__ se,
    const float* __restrict__ mc, const float* __restrict__ me,
    const float* __restrict__ E,  const float* __restrict__ tau,
    float* __restrict__ We, float* __restrict__ A, float* __restrict__ S,
    float* __restrict__ R,  float* __restrict__ DTT) {
    int i = blockIdx.x;
    int lane = threadIdx.x;
    float a = 0.f, s = 0.f, r = 0.f;
    for (int j = lane; j < NN; j += 64) {
        float wc = sc[i * NN + j] * (mc[i * NN + j] * 0.01f);
        a += wc * E[i * NN + j];
        s += wc;
        float we = se[i * NN + j] * ((me[i * NN + j] + me[j * NN + i]) * 0.01f);
        We[i * NN + j] = we;
        r += we;
    }
    #pragma unroll
    for (int o = 32; o > 0; o >>= 1) {
        a += __shfl_down(a, o);
        s += __shfl_down(s, o);
        r += __shfl_down(r, o);
    }
    if (lane == 0) {
        A[i] = a;
        S[i] = s;
        R[i] = r;
        DTT[i] = 0.01f / tau[i];
    }
}

// ---------------- main: fused GEMM + elementwise ----------------
__global__ __launch_bounds__(256) void lic_main_kernel(
    const float* __restrict__ input, const float* __restrict__ hidden,
    const float* __restrict__ We, const float* __restrict__ A,
    const float* __restrict__ S, const float* __restrict__ R,
    const float* __restrict__ DTT, const float* __restrict__ bias,
    float* __restrict__ out) {
    __shared__ float xs[NN * TT];   // xs[j][t], 76.8 KB

    const int blk = blockIdx.x;             // b * (TTOT/TT) + tchunk
    const int b = blk / (TTOT / TT);
    const int t0 = (blk % (TTOT / TT)) * TT;
    const int tid = threadIdx.x;
    const int t = tid & 63;                 // lane = t within tile
    const int ig = tid >> 6;                // wave id 0..3
    const int gt = t0 + t;                  // global t

    // ---- stage x[b, :, t-tile] into LDS (x = time-shifted hidden) ----
    const float* hb = hidden + (size_t)b * NN * TTOT;
    const int src_t = (gt == 0) ? 0 : (gt - 1);   // safe address when gt==0
    for (int j = ig; j < NN; j += 4) {
        float v = hb[(size_t)j * TTOT + src_t];
        xs[j * TT + t] = (gt == 0) ? 0.f : v;
    }
    __syncthreads();

    const int ibase = ig * 75;              // each wave owns 75 rows
    const size_t bOff = (size_t)b * NN * TTOT;

    for (int i0 = 0; i0 < 75; i0 += 15) {
        float acc[15];
        #pragma unroll
        for (int u = 0; u < 15; u++) acc[u] = 0.f;

        // wave-uniform row pointers -> scalar loads
        const float* rowp[15];
        #pragma unroll
        for (int u = 0; u < 15; u++)
            rowp[u] = We + __builtin_amdgcn_readfirstlane((ibase + i0 + u) * NN);

        for (int j = 0; j < NN; j++) {
            float xv = xs[j * TT + t];
            #pragma unroll
            for (int u = 0; u < 15; u++)
                acc[u] += rowp[u][j] * xv;
        }

        #pragma unroll
        for (int u = 0; u < 15; u++) {
            const int i = ibase + i0 + u;
            const float x = xs[i * TT + t];
            const float chem = (A[i] - x * S[i]) * fmaxf(x, 0.f);
            const float elec = acc[u] - R[i] * x;
            const size_t o = bOff + (size_t)i * TTOT + gt;
            const float inp = input[o];
            const float mu = DTT[i] * (chem + elec + bias[i] + inp - x) + x;
            out[o] = mu;                    // mu
            out[BNT + o] = chem;            // chem_in
            out[2 * BNT + o] = elec;        // elec_in
        }
    }
}

extern "C" void kernel_launch(void* const* d_in, const int* in_sizes, int n_in,
                              void* d_out, int out_size, void* d_ws, size_t ws_size,
                              hipStream_t stream) {
    const float* input  = (const float*)d_in[0];
    const float* hidden = (const float*)d_in[1];
    const float* sc     = (const float*)d_in[2];
    const float* se     = (const float*)d_in[3];
    const float* mc     = (const float*)d_in[4];
    const float* me     = (const float*)d_in[5];
    const float* E      = (const float*)d_in[6];
    const float* bias   = (const float*)d_in[7];
    const float* tau    = (const float*)d_in[8];
    float* out = (float*)d_out;

    float* ws  = (float*)d_ws;
    float* We  = ws;             // 300*300
    float* A   = ws + 90000;     // 300
    float* S   = ws + 90300;     // 300
    float* R   = ws + 90600;     // 300
    float* DTT = ws + 90900;     // 300

    lic_prep_kernel<<<NN, 64, 0, stream>>>(sc, se, mc, me, E, tau, We, A, S, R, DTT);
    lic_main_kernel<<<TB * (TTOT / TT), 256, 0, stream>>>(input, hidden, We, A, S, R,
                                                          DTT, bias, out);
}

// Round 2
// 357.653 us; speedup vs baseline: 2.2491x; 2.2491x over previous
//
#include <hip/hip_runtime.h>
#include <hip/hip_bf16.h>

#define NN 300
#define TB 16
#define TTOT 4096
#define KP 320          // padded K (10 x 32)
#define MP 384          // padded M (3 x 128)
#define BM 128
#define BTT 128         // t-tile
#define BK 32
#define NKS (KP / BK)   // 10
#define LDA 40          // LDS row stride in bf16 elems (pad 32 -> 40, 2-way max)
#define BNT ((size_t)TB * NN * TTOT)

typedef __attribute__((ext_vector_type(8))) short short8;
typedef __attribute__((ext_vector_type(4))) float f32x4;

static __device__ __forceinline__ ushort f2bf(float f) {
    __hip_bfloat16 h = __float2bfloat16(f);
    return *reinterpret_cast<ushort*>(&h);
}

// ---------------- prep: bf16 W_e (padded, zero-filled) + per-row scalars ----------------
__global__ __launch_bounds__(64) void lic_prep(
    const float* __restrict__ sc, const float* __restrict__ se,
    const float* __restrict__ mc, const float* __restrict__ me,
    const float* __restrict__ E,  const float* __restrict__ bias,
    const float* __restrict__ tau,
    ushort* __restrict__ Web, float* __restrict__ scal /* [MP][5] */) {
    const int i = blockIdx.x;       // 0..MP-1
    const int lane = threadIdx.x;
    float a = 0.f, s = 0.f, r = 0.f;
    for (int j = lane; j < KP; j += 64) {
        float we = 0.f;
        if (i < NN && j < NN) {
            float wc = sc[i * NN + j] * (mc[i * NN + j] * 0.01f);
            a += wc * E[i * NN + j];
            s += wc;
            we = se[i * NN + j] * ((me[i * NN + j] + me[j * NN + i]) * 0.01f);
            r += we;
        }
        Web[(size_t)i * KP + j] = f2bf(we);
    }
    #pragma unroll
    for (int o = 32; o > 0; o >>= 1) {
        a += __shfl_down(a, o);
        s += __shfl_down(s, o);
        r += __shfl_down(r, o);
    }
    if (lane == 0) {
        float* p = &scal[i * 5];
        p[0] = a;
        p[1] = s;
        p[2] = r;
        p[3] = (i < NN) ? (0.01f / tau[i]) : 0.f;
        p[4] = (i < NN) ? bias[i] : 0.f;
    }
}

// ---------------- main: bf16 MFMA GEMM + fused elementwise epilogue ----------------
__global__ __launch_bounds__(256) void lic_mfma(
    const float* __restrict__ input, const float* __restrict__ hidden,
    const ushort* __restrict__ Web, const float* __restrict__ scal,
    float* __restrict__ out) {
    __shared__ ushort As[2][BM * LDA];   // [row][k] bf16, padded
    __shared__ ushort Bs[2][BTT * LDA];  // [t][k]  bf16 (transposed x-tile), padded

    const int blk = blockIdx.x;          // b*96 + mt*32 + tt
    const int b  = blk / 96;
    const int mt = (blk % 96) / 32;
    const int tt = blk % 32;
    const int m0 = mt * BM;
    const int t0 = tt * BTT;
    const int tid = threadIdx.x;
    const int l   = tid & 63;
    const int w   = tid >> 6;
    const int wrow = (w >> 1) * 64;
    const int wcol = (w & 1) * 64;
    const int lo = l & 15, hi = l >> 4;

    const float* hb = hidden + (size_t)b * NN * TTOT;

    f32x4 acc[4][4];
    #pragma unroll
    for (int fr = 0; fr < 4; fr++)
        #pragma unroll
        for (int fc = 0; fc < 4; fc++)
            acc[fr][fc] = (f32x4){0.f, 0.f, 0.f, 0.f};

    // staging registers
    short8 aReg[2];
    float  bReg[16];
    const int tl = tid & 127;            // t_local 0..127
    const int jg = (tid >> 7) * 16;      // j group base (0 or 16)
    const int gt = t0 + tl;              // global t for B staging

    auto LOAD = [&](int ks) {
        const int k0 = ks * BK;
        #pragma unroll
        for (int u = 0; u < 2; u++) {
            const int c = tid + u * 256;           // chunk 0..511
            const int row = c >> 2, ko = (c & 3) * 8;
            aReg[u] = *(const short8*)&Web[(size_t)(m0 + row) * KP + k0 + ko];
        }
        #pragma unroll
        for (int e = 0; e < 16; e++) {
            const int j = k0 + jg + e;             // global k-row
            float v = 0.f;
            if (j < NN && gt > 0) v = hb[(size_t)j * TTOT + gt - 1];
            bReg[e] = v;
        }
    };
    auto WRITE = [&](int buf) {
        #pragma unroll
        for (int u = 0; u < 2; u++) {
            const int c = tid + u * 256;
            const int row = c >> 2, ko = (c & 3) * 8;
            *(short8*)&As[buf][row * LDA + ko] = aReg[u];
        }
        short8 w0, w1;
        #pragma unroll
        for (int e = 0; e < 8; e++) {
            w0[e] = (short)f2bf(bReg[e]);
            w1[e] = (short)f2bf(bReg[e + 8]);
        }
        *(short8*)&Bs[buf][tl * LDA + jg]     = w0;
        *(short8*)&Bs[buf][tl * LDA + jg + 8] = w1;
    };

    LOAD(0); WRITE(0);
    __syncthreads();

    for (int ks = 0; ks < NKS; ks++) {
        const int buf = ks & 1;
        if (ks + 1 < NKS) LOAD(ks + 1);    // issue next-tile global loads early

        short8 af[4], bf[4];
        #pragma unroll
        for (int fr = 0; fr < 4; fr++)
            af[fr] = *(const short8*)&As[buf][(wrow + fr * 16 + lo) * LDA + hi * 8];
        #pragma unroll
        for (int fc = 0; fc < 4; fc++)
            bf[fc] = *(const short8*)&Bs[buf][(wcol + fc * 16 + lo) * LDA + hi * 8];
        #pragma unroll
        for (int fr = 0; fr < 4; fr++)
            #pragma unroll
            for (int fc = 0; fc < 4; fc++)
                acc[fr][fc] = __builtin_amdgcn_mfma_f32_16x16x32_bf16(
                    af[fr], bf[fc], acc[fr][fc], 0, 0, 0);

        if (ks + 1 < NKS) WRITE(buf ^ 1);
        __syncthreads();
    }

    // ---- epilogue: elec = acc - R*x ; chem ; mu ; 3 stores ----
    const size_t bOff = (size_t)b * NN * TTOT;
    #pragma unroll
    for (int fr = 0; fr < 4; fr++) {
        const int ib = m0 + wrow + fr * 16 + hi * 4;
        float sA[4], sS[4], sR[4], sD[4], sB[4];
        #pragma unroll
        for (int r = 0; r < 4; r++) {
            const float* p = &scal[(ib + r) * 5];
            sA[r] = p[0]; sS[r] = p[1]; sR[r] = p[2]; sD[r] = p[3]; sB[r] = p[4];
        }
        #pragma unroll
        for (int fc = 0; fc < 4; fc++) {
            const int t = t0 + wcol + fc * 16 + lo;
            #pragma unroll
            for (int r = 0; r < 4; r++) {
                const int i = ib + r;
                if (i < NN) {
                    const size_t o = bOff + (size_t)i * TTOT + t;
                    const float x = (t > 0) ? hb[(size_t)i * TTOT + t - 1] : 0.f;
                    const float elec = acc[fr][fc][r] - sR[r] * x;
                    const float chem = (sA[r] - x * sS[r]) * fmaxf(x, 0.f);
                    const float mu = sD[r] * (chem + elec + sB[r] + input[o] - x) + x;
                    out[o] = mu;
                    out[BNT + o] = chem;
                    out[2 * BNT + o] = elec;
                }
            }
        }
    }
}

extern "C" void kernel_launch(void* const* d_in, const int* in_sizes, int n_in,
                              void* d_out, int out_size, void* d_ws, size_t ws_size,
                              hipStream_t stream) {
    const float* input  = (const float*)d_in[0];
    const float* hidden = (const float*)d_in[1];
    const float* sc     = (const float*)d_in[2];
    const float* se     = (const float*)d_in[3];
    const float* mc     = (const float*)d_in[4];
    const float* me     = (const float*)d_in[5];
    const float* E      = (const float*)d_in[6];
    const float* bias   = (const float*)d_in[7];
    const float* tau    = (const float*)d_in[8];
    float* out = (float*)d_out;

    ushort* Web = (ushort*)d_ws;                            // MP*KP bf16 = 245,760 B
    float*  scal = (float*)((char*)d_ws + (size_t)MP * KP * 2);  // MP*5 floats

    lic_prep<<<MP, 64, 0, stream>>>(sc, se, mc, me, E, bias, tau, Web, scal);
    lic_mfma<<<TB * 96, 256, 0, stream>>>(input, hidden, Web, scal, out);
}

// Round 3
// 265.599 us; speedup vs baseline: 3.0286x; 1.3466x over previous
//
#include <hip/hip_runtime.h>
#include <hip/hip_bf16.h>

#define NN 300
#define TB 16
#define TTOT 4096
#define KP 320          // padded K (10 x 32)
#define MP 384          // padded M (6 x 64)
#define BNT ((size_t)TB * NN * TTOT)

typedef __attribute__((ext_vector_type(8))) short short8;
typedef __attribute__((ext_vector_type(4))) float f32x4;

static __device__ __forceinline__ ushort f2bf(float f) {
    __hip_bfloat16 h = __float2bfloat16(f);
    return *reinterpret_cast<ushort*>(&h);
}

// ---------------- prep: bf16 W_e (padded, zero-filled) + per-row scalars ----------------
__global__ __launch_bounds__(64) void lic_prep(
    const float* __restrict__ sc, const float* __restrict__ se,
    const float* __restrict__ mc, const float* __restrict__ me,
    const float* __restrict__ E,  const float* __restrict__ bias,
    const float* __restrict__ tau,
    ushort* __restrict__ Web, float* __restrict__ scal /* [MP][5] */) {
    const int i = blockIdx.x;       // 0..MP-1
    const int lane = threadIdx.x;
    float a = 0.f, s = 0.f, r = 0.f;
    for (int j = lane; j < KP; j += 64) {
        float we = 0.f;
        if (i < NN && j < NN) {
            float wc = sc[i * NN + j] * (mc[i * NN + j] * 0.01f);
            a += wc * E[i * NN + j];
            s += wc;
            we = se[i * NN + j] * ((me[i * NN + j] + me[j * NN + i]) * 0.01f);
            r += we;
        }
        Web[(size_t)i * KP + j] = f2bf(we);
    }
    #pragma unroll
    for (int o = 32; o > 0; o >>= 1) {
        a += __shfl_down(a, o);
        s += __shfl_down(s, o);
        r += __shfl_down(r, o);
    }
    if (lane == 0) {
        float* p = &scal[i * 5];
        p[0] = a;
        p[1] = s;
        p[2] = r;
        p[3] = (i < NN) ? (0.01f / tau[i]) : 0.f;
        p[4] = (i < NN) ? bias[i] : 0.f;
    }
}

// ---------------- transpose: xT[b][t][j] = bf16 time-shifted hidden ----------------
__global__ __launch_bounds__(256) void lic_xpose(
    const float* __restrict__ hidden, ushort* __restrict__ xT) {
    __shared__ float xs[64][65];
    const int blk = blockIdx.x;            // b*320 + jt*64 + tt
    const int b  = blk / 320;
    const int r  = blk % 320;
    const int j0 = (r / 64) * 64;
    const int t0 = (r % 64) * 64;
    const int tid = threadIdx.x;
    const int lane = tid & 63;
    const int row  = tid >> 6;

    const float* hb = hidden + (size_t)b * NN * TTOT;
    const int gt = t0 + lane;
    #pragma unroll
    for (int u = 0; u < 16; u++) {
        const int jj = row + u * 4;
        const int j = j0 + jj;
        float v = 0.f;
        if (j < NN && gt > 0) v = hb[(size_t)j * TTOT + gt - 1];
        xs[jj][lane] = v;
    }
    __syncthreads();
    ushort* xb = xT + (size_t)b * TTOT * KP;
    #pragma unroll
    for (int u = 0; u < 16; u++) {
        const int tt2 = row + u * 4;
        xb[(size_t)(t0 + tt2) * KP + j0 + lane] = f2bf(xs[lane][tt2]);
    }
}

// ---------------- main: LDS-free, barrier-free MFMA GEMM + fused epilogue ----------------
__global__ __launch_bounds__(256) void lic_main(
    const float* __restrict__ input, const float* __restrict__ hidden,
    const ushort* __restrict__ xT, const ushort* __restrict__ Web,
    const float* __restrict__ scal, float* __restrict__ out) {
    const int blk = blockIdx.x;            // b*96 + tc*6 + mi
    const int b  = blk / 96;
    const int r  = blk % 96;
    const int tc = r / 6;
    const int m0 = (r % 6) * 64;
    const int tid = threadIdx.x;
    const int l  = tid & 63;
    const int w  = tid >> 6;
    const int t0 = tc * 256 + w * 64;      // each wave: 64x64 tile at (m0, t0)
    const int lo = l & 15, hi = l >> 4;

    f32x4 acc[4][4];
    #pragma unroll
    for (int fr = 0; fr < 4; fr++)
        #pragma unroll
        for (int fc = 0; fc < 4; fc++)
            acc[fr][fc] = (f32x4){0.f, 0.f, 0.f, 0.f};

    const ushort* Ab = Web + (size_t)(m0 + lo) * KP + hi * 8;
    const ushort* Bb = xT + ((size_t)b * TTOT + t0 + lo) * KP + hi * 8;

    #pragma unroll 2
    for (int ks = 0; ks < KP / 32; ks++) {
        short8 af[4], bf[4];
        #pragma unroll
        for (int fr = 0; fr < 4; fr++)
            af[fr] = *(const short8*)&Ab[(size_t)(fr * 16) * KP + ks * 32];
        #pragma unroll
        for (int fc = 0; fc < 4; fc++)
            bf[fc] = *(const short8*)&Bb[(size_t)(fc * 16) * KP + ks * 32];
        #pragma unroll
        for (int fr = 0; fr < 4; fr++)
            #pragma unroll
            for (int fc = 0; fc < 4; fc++)
                acc[fr][fc] = __builtin_amdgcn_mfma_f32_16x16x32_bf16(
                    af[fr], bf[fc], acc[fr][fc], 0, 0, 0);
    }

    // ---- epilogue: elec = acc - R*x ; chem ; mu ; 3 stores ----
    const size_t bOff = (size_t)b * NN * TTOT;
    const float* hb = hidden + bOff;
    #pragma unroll
    for (int fr = 0; fr < 4; fr++) {
        const int ib = m0 + fr * 16 + hi * 4;
        float sA[4], sS[4], sR[4], sD[4], sB[4];
        #pragma unroll
        for (int rr = 0; rr < 4; rr++) {
            const float* p = &scal[(ib + rr) * 5];
            sA[rr] = p[0]; sS[rr] = p[1]; sR[rr] = p[2]; sD[rr] = p[3]; sB[rr] = p[4];
        }
        #pragma unroll
        for (int fc = 0; fc < 4; fc++) {
            const int t = t0 + fc * 16 + lo;
            #pragma unroll
            for (int rr = 0; rr < 4; rr++) {
                const int i = ib + rr;
                if (i < NN) {
                    const size_t o = bOff + (size_t)i * TTOT + t;
                    const float x = (t > 0) ? hb[(size_t)i * TTOT + t - 1] : 0.f;
                    const float elec = acc[fr][fc][rr] - sR[rr] * x;
                    const float chem = (sA[rr] - x * sS[rr]) * fmaxf(x, 0.f);
                    const float mu = sD[rr] * (chem + elec + sB[rr] + input[o] - x) + x;
                    out[o] = mu;
                    out[BNT + o] = chem;
                    out[2 * BNT + o] = elec;
                }
            }
        }
    }
}

// ================= fallback path (validated R1 kernel) =================
#define BM 128
#define BTT 128
#define BK 32
#define NKS (KP / BK)
#define LDA 40

__global__ __launch_bounds__(256) void lic_mfma_fb(
    const float* __restrict__ input, const float* __restrict__ hidden,
    const ushort* __restrict__ Web, const float* __restrict__ scal,
    float* __restrict__ out) {
    __shared__ ushort As[2][BM * LDA];
    __shared__ ushort Bs[2][BTT * LDA];

    const int blk = blockIdx.x;
    const int b  = blk / 96;
    const int mt = (blk % 96) / 32;
    const int tt = blk % 32;
    const int m0 = mt * BM;
    const int t0 = tt * BTT;
    const int tid = threadIdx.x;
    const int l   = tid & 63;
    const int w   = tid >> 6;
    const int wrow = (w >> 1) * 64;
    const int wcol = (w & 1) * 64;
    const int lo = l & 15, hi = l >> 4;

    const float* hb = hidden + (size_t)b * NN * TTOT;

    f32x4 acc[4][4];
    #pragma unroll
    for (int fr = 0; fr < 4; fr++)
        #pragma unroll
        for (int fc = 0; fc < 4; fc++)
            acc[fr][fc] = (f32x4){0.f, 0.f, 0.f, 0.f};

    short8 aReg[2];
    float  bReg[16];
    const int tl = tid & 127;
    const int jg = (tid >> 7) * 16;
    const int gt = t0 + tl;

    auto LOAD = [&](int ks) {
        const int k0 = ks * BK;
        #pragma unroll
        for (int u = 0; u < 2; u++) {
            const int c = tid + u * 256;
            const int row = c >> 2, ko = (c & 3) * 8;
            aReg[u] = *(const short8*)&Web[(size_t)(m0 + row) * KP + k0 + ko];
        }
        #pragma unroll
        for (int e = 0; e < 16; e++) {
            const int j = k0 + jg + e;
            float v = 0.f;
            if (j < NN && gt > 0) v = hb[(size_t)j * TTOT + gt - 1];
            bReg[e] = v;
        }
    };
    auto WRITE = [&](int buf) {
        #pragma unroll
        for (int u = 0; u < 2; u++) {
            const int c = tid + u * 256;
            const int row = c >> 2, ko = (c & 3) * 8;
            *(short8*)&As[buf][row * LDA + ko] = aReg[u];
        }
        short8 w0, w1;
        #pragma unroll
        for (int e = 0; e < 8; e++) {
            w0[e] = (short)f2bf(bReg[e]);
            w1[e] = (short)f2bf(bReg[e + 8]);
        }
        *(short8*)&Bs[buf][tl * LDA + jg]     = w0;
        *(short8*)&Bs[buf][tl * LDA + jg + 8] = w1;
    };

    LOAD(0); WRITE(0);
    __syncthreads();

    for (int ks = 0; ks < NKS; ks++) {
        const int buf = ks & 1;
        if (ks + 1 < NKS) LOAD(ks + 1);

        short8 af[4], bf[4];
        #pragma unroll
        for (int fr = 0; fr < 4; fr++)
            af[fr] = *(const short8*)&As[buf][(wrow + fr * 16 + lo) * LDA + hi * 8];
        #pragma unroll
        for (int fc = 0; fc < 4; fc++)
            bf[fc] = *(const short8*)&Bs[buf][(wcol + fc * 16 + lo) * LDA + hi * 8];
        #pragma unroll
        for (int fr = 0; fr < 4; fr++)
            #pragma unroll
            for (int fc = 0; fc < 4; fc++)
                acc[fr][fc] = __builtin_amdgcn_mfma_f32_16x16x32_bf16(
                    af[fr], bf[fc], acc[fr][fc], 0, 0, 0);

        if (ks + 1 < NKS) WRITE(buf ^ 1);
        __syncthreads();
    }

    const size_t bOff = (size_t)b * NN * TTOT;
    #pragma unroll
    for (int fr = 0; fr < 4; fr++) {
        const int ib = m0 + wrow + fr * 16 + hi * 4;
        float sA[4], sS[4], sR[4], sD[4], sB[4];
        #pragma unroll
        for (int rr = 0; rr < 4; rr++) {
            const float* p = &scal[(ib + rr) * 5];
            sA[rr] = p[0]; sS[rr] = p[1]; sR[rr] = p[2]; sD[rr] = p[3]; sB[rr] = p[4];
        }
        #pragma unroll
        for (int fc = 0; fc < 4; fc++) {
            const int t = t0 + wcol + fc * 16 + lo;
            #pragma unroll
            for (int rr = 0; rr < 4; rr++) {
                const int i = ib + rr;
                if (i < NN) {
                    const size_t o = bOff + (size_t)i * TTOT + t;
                    const float x = (t > 0) ? hb[(size_t)i * TTOT + t - 1] : 0.f;
                    const float elec = acc[fr][fc][rr] - sR[rr] * x;
                    const float chem = (sA[rr] - x * sS[rr]) * fmaxf(x, 0.f);
                    const float mu = sD[rr] * (chem + elec + sB[rr] + input[o] - x) + x;
                    out[o] = mu;
                    out[BNT + o] = chem;
                    out[2 * BNT + o] = elec;
                }
            }
        }
    }
}

extern "C" void kernel_launch(void* const* d_in, const int* in_sizes, int n_in,
                              void* d_out, int out_size, void* d_ws, size_t ws_size,
                              hipStream_t stream) {
    const float* input  = (const float*)d_in[0];
    const float* hidden = (const float*)d_in[1];
    const float* sc     = (const float*)d_in[2];
    const float* se     = (const float*)d_in[3];
    const float* mc     = (const float*)d_in[4];
    const float* me     = (const float*)d_in[5];
    const float* E      = (const float*)d_in[6];
    const float* bias   = (const float*)d_in[7];
    const float* tau    = (const float*)d_in[8];
    float* out = (float*)d_out;

    ushort* Web = (ushort*)d_ws;                                   // 245,760 B
    float*  scal = (float*)((char*)d_ws + (size_t)MP * KP * 2);    // 7,680 B
    ushort* xT  = (ushort*)((char*)d_ws + 253440);                 // 41,943,040 B
    const size_t need = 253440 + (size_t)TB * TTOT * KP * 2;

    lic_prep<<<MP, 64, 0, stream>>>(sc, se, mc, me, E, bias, tau, Web, scal);

    if (ws_size >= need) {
        lic_xpose<<<TB * 320, 256, 0, stream>>>(hidden, xT);
        lic_main<<<TB * 96, 256, 0, stream>>>(input, hidden, xT, Web, scal, out);
    } else {
        lic_mfma_fb<<<TB * 96, 256, 0, stream>>>(input, hidden, Web, scal, out);
    }
}

// Round 4
// 241.431 us; speedup vs baseline: 3.3317x; 1.1001x over previous
//
#include <hip/hip_runtime.h>
#include <hip/hip_bf16.h>

#define NN 300
#define TB 16
#define TTOT 4096
#define KP 320            // padded K (10 x 32)
#define MPAD 320          // padded M for main path (5 x 64)
#define MP 384            // padded M for fallback/scal table
#define NKS 10
#define BNT ((size_t)TB * NN * TTOT)

typedef __attribute__((ext_vector_type(8))) short short8;
typedef __attribute__((ext_vector_type(4))) float f32x4;

static __device__ __forceinline__ ushort f2bf(float f) {
    __hip_bfloat16 h = __float2bfloat16(f);
    return *reinterpret_cast<ushort*>(&h);
}

// ws layout (bytes):
//   Web   @ 0        : 384*320*2   = 245760   (row-major, fallback path)
//   scal  @ 245760   : 384*5*4     = 7680
//   WebP  @ 253440   : 20*10*1024  = 204800   (fragment-packed)
//   xP    @ 458240   : 16*256*10*1024 = 41943040
#define OFF_SCAL 245760
#define OFF_WEBP 253440
#define OFF_XP   458240
#define WS_NEED  (OFF_XP + (size_t)TB * 256 * NKS * 1024)

// ---------------- prep: W_e (row-major + packed) + per-row scalars ----------------
__global__ __launch_bounds__(64) void lic_prep(
    const float* __restrict__ sc, const float* __restrict__ se,
    const float* __restrict__ mc, const float* __restrict__ me,
    const float* __restrict__ E,  const float* __restrict__ bias,
    const float* __restrict__ tau,
    ushort* __restrict__ Web, ushort* __restrict__ WebP,
    float* __restrict__ scal /* [MP][5] */) {
    const int i = blockIdx.x;       // 0..MP-1
    const int lane = threadIdx.x;
    float a = 0.f, s = 0.f, r = 0.f;
    for (int j = lane; j < KP; j += 64) {
        float we = 0.f;
        if (i < NN && j < NN) {
            float wc = sc[i * NN + j] * (mc[i * NN + j] * 0.01f);
            a += wc * E[i * NN + j];
            s += wc;
            we = se[i * NN + j] * ((me[i * NN + j] + me[j * NN + i]) * 0.01f);
            r += we;
        }
        const ushort bf = f2bf(we);
        Web[(size_t)i * KP + j] = bf;
        if (i < MPAD) {
            const int mb = i >> 4, ri = i & 15;
            const int kb = j >> 5, ko = (j >> 3) & 3, e = j & 7;
            WebP[((size_t)(mb * NKS + kb) * 64 + (ri + ko * 16)) * 8 + e] = bf;
        }
    }
    #pragma unroll
    for (int o = 32; o > 0; o >>= 1) {
        a += __shfl_down(a, o);
        s += __shfl_down(s, o);
        r += __shfl_down(r, o);
    }
    if (lane == 0) {
        float* p = &scal[i * 5];
        p[0] = a;
        p[1] = s;
        p[2] = r;
        p[3] = (i < NN) ? (0.01f / tau[i]) : 0.f;
        p[4] = (i < NN) ? bias[i] : 0.f;
    }
}

// ---------------- xpose: packed bf16 fragments of time-shifted hidden ----------------
// xP[b][tbg(256)][ks(10)][lane(64)][e(8)] ; fragment elem = x[b][t=tbg*16+(l&15)][k=ks*32+(l>>4)*8+e]
__global__ __launch_bounds__(256) void lic_xpose(
    const float* __restrict__ hidden, ushort* __restrict__ xP) {
    __shared__ float xs[64][65];
    const int nwg = TB * 5 * 64;                 // 5120
    const int blk0 = blockIdx.x;
    const int blk = (blk0 % 8) * (nwg / 8) + blk0 / 8;   // XCD chunking (bijective)
    const int b  = blk / 320;
    const int r  = blk % 320;
    const int j0 = (r / 64) * 64;
    const int t0 = (r % 64) * 64;
    const int tid = threadIdx.x;
    const int lane = tid & 63;
    const int row  = tid >> 6;
    const int lo = lane & 15, hi = lane >> 4;

    const float* hb = hidden + (size_t)b * NN * TTOT;
    const int gt = t0 + lane;
    #pragma unroll
    for (int u = 0; u < 16; u++) {
        const int jj = row + u * 4;
        const int j = j0 + jj;
        float v = 0.f;
        if (j < NN && gt > 0) v = hb[(size_t)j * TTOT + gt - 1];
        xs[jj][lane] = v;
    }
    __syncthreads();

    // wave w packs t-subtile tb=w (16 t's), two k-fragments (j0..j0+63 = 2 ks)
    ushort* xb = xP + ((size_t)b * 256 + (t0 >> 4) + row) * (NKS * 512);
    #pragma unroll
    for (int ksl = 0; ksl < 2; ksl++) {
        const int ksg = (j0 >> 5) + ksl;
        short8 v;
        #pragma unroll
        for (int e = 0; e < 8; e++)
            v[e] = (short)f2bf(xs[ksl * 32 + hi * 8 + e][row * 16 + lo]);
        *(short8*)&xb[(size_t)ksg * 512 + lane * 8] = v;
    }
}

// ---------------- main: barrier-free MFMA GEMM on packed fragments ----------------
__global__ __launch_bounds__(256) void lic_main(
    const float* __restrict__ input, const float* __restrict__ hidden,
    const ushort* __restrict__ xP, const ushort* __restrict__ WebP,
    const float* __restrict__ scal, float* __restrict__ out) {
    const int nwg = TB * 80;                     // 1280
    const int blk0 = blockIdx.x;
    const int blk = (blk0 % 8) * (nwg / 8) + blk0 / 8;   // XCD chunking (bijective)
    const int b  = blk / 80;
    const int r  = blk % 80;
    const int tc = r / 5;
    const int m0 = (r % 5) * 64;
    const int tid = threadIdx.x;
    const int l  = tid & 63;
    const int w  = tid >> 6;
    const int t0 = tc * 256 + w * 64;            // wave tile: 64 rows x 64 t
    const int lo = l & 15, hi = l >> 4;

    f32x4 acc[4][4];
    #pragma unroll
    for (int fr = 0; fr < 4; fr++)
        #pragma unroll
        for (int fc = 0; fc < 4; fc++)
            acc[fr][fc] = (f32x4){0.f, 0.f, 0.f, 0.f};

    const ushort* Ap = WebP + (size_t)(m0 >> 4) * (NKS * 512) + l * 8;
    const ushort* Bp = xP + ((size_t)b * 256 + (t0 >> 4)) * (NKS * 512) + l * 8;

    short8 abuf[2][4], bbuf[2][4];
    #pragma unroll
    for (int fr = 0; fr < 4; fr++) {
        abuf[0][fr] = *(const short8*)&Ap[(size_t)fr * (NKS * 512)];
        bbuf[0][fr] = *(const short8*)&Bp[(size_t)fr * (NKS * 512)];
    }
    #pragma unroll
    for (int ks = 0; ks < NKS; ks++) {
        const int c = ks & 1, n = c ^ 1;
        if (ks + 1 < NKS) {
            #pragma unroll
            for (int fr = 0; fr < 4; fr++) {
                abuf[n][fr] = *(const short8*)&Ap[(size_t)fr * (NKS * 512) + (ks + 1) * 512];
                bbuf[n][fr] = *(const short8*)&Bp[(size_t)fr * (NKS * 512) + (ks + 1) * 512];
            }
        }
        #pragma unroll
        for (int fr = 0; fr < 4; fr++)
            #pragma unroll
            for (int fc = 0; fc < 4; fc++)
                acc[fr][fc] = __builtin_amdgcn_mfma_f32_16x16x32_bf16(
                    abuf[c][fr], bbuf[c][fc], acc[fr][fc], 0, 0, 0);
    }

    // ---- epilogue: elec = acc - R*x ; chem ; mu ; 3 stores ----
    const size_t bOff = (size_t)b * NN * TTOT;
    const float* hb = hidden + bOff;
    #pragma unroll
    for (int fr = 0; fr < 4; fr++) {
        const int ib = m0 + fr * 16 + hi * 4;
        float sA[4], sS[4], sR[4], sD[4], sB[4];
        #pragma unroll
        for (int rr = 0; rr < 4; rr++) {
            const float* p = &scal[(ib + rr) * 5];
            sA[rr] = p[0]; sS[rr] = p[1]; sR[rr] = p[2]; sD[rr] = p[3]; sB[rr] = p[4];
        }
        #pragma unroll
        for (int fc = 0; fc < 4; fc++) {
            const int t = t0 + fc * 16 + lo;
            #pragma unroll
            for (int rr = 0; rr < 4; rr++) {
                const int i = ib + rr;
                if (i < NN) {
                    const size_t o = bOff + (size_t)i * TTOT + t;
                    const float x = (t > 0) ? hb[(size_t)i * TTOT + t - 1] : 0.f;
                    const float elec = acc[fr][fc][rr] - sR[rr] * x;
                    const float chem = (sA[rr] - x * sS[rr]) * fmaxf(x, 0.f);
                    const float mu = sD[rr] * (chem + elec + sB[rr] + input[o] - x) + x;
                    out[o] = mu;
                    out[BNT + o] = chem;
                    out[2 * BNT + o] = elec;
                }
            }
        }
    }
}

// ================= fallback path (validated R1 kernel, row-major Web) =================
#define BM 128
#define BTT 128
#define BK 32
#define LDA 40

__global__ __launch_bounds__(256) void lic_mfma_fb(
    const float* __restrict__ input, const float* __restrict__ hidden,
    const ushort* __restrict__ Web, const float* __restrict__ scal,
    float* __restrict__ out) {
    __shared__ ushort As[2][BM * LDA];
    __shared__ ushort Bs[2][BTT * LDA];

    const int blk = blockIdx.x;
    const int b  = blk / 96;
    const int mt = (blk % 96) / 32;
    const int tt = blk % 32;
    const int m0 = mt * BM;
    const int t0 = tt * BTT;
    const int tid = threadIdx.x;
    const int l   = tid & 63;
    const int w   = tid >> 6;
    const int wrow = (w >> 1) * 64;
    const int wcol = (w & 1) * 64;
    const int lo = l & 15, hi = l >> 4;

    const float* hb = hidden + (size_t)b * NN * TTOT;

    f32x4 acc[4][4];
    #pragma unroll
    for (int fr = 0; fr < 4; fr++)
        #pragma unroll
        for (int fc = 0; fc < 4; fc++)
            acc[fr][fc] = (f32x4){0.f, 0.f, 0.f, 0.f};

    short8 aReg[2];
    float  bReg[16];
    const int tl = tid & 127;
    const int jg = (tid >> 7) * 16;
    const int gt = t0 + tl;

    auto LOAD = [&](int ks) {
        const int k0 = ks * BK;
        #pragma unroll
        for (int u = 0; u < 2; u++) {
            const int c = tid + u * 256;
            const int row = c >> 2, ko = (c & 3) * 8;
            aReg[u] = *(const short8*)&Web[(size_t)(m0 + row) * KP + k0 + ko];
        }
        #pragma unroll
        for (int e = 0; e < 16; e++) {
            const int j = k0 + jg + e;
            float v = 0.f;
            if (j < NN && gt > 0) v = hb[(size_t)j * TTOT + gt - 1];
            bReg[e] = v;
        }
    };
    auto WRITE = [&](int buf) {
        #pragma unroll
        for (int u = 0; u < 2; u++) {
            const int c = tid + u * 256;
            const int row = c >> 2, ko = (c & 3) * 8;
            *(short8*)&As[buf][row * LDA + ko] = aReg[u];
        }
        short8 w0, w1;
        #pragma unroll
        for (int e = 0; e < 8; e++) {
            w0[e] = (short)f2bf(bReg[e]);
            w1[e] = (short)f2bf(bReg[e + 8]);
        }
        *(short8*)&Bs[buf][tl * LDA + jg]     = w0;
        *(short8*)&Bs[buf][tl * LDA + jg + 8] = w1;
    };

    LOAD(0); WRITE(0);
    __syncthreads();

    for (int ks = 0; ks < NKS; ks++) {
        const int buf = ks & 1;
        if (ks + 1 < NKS) LOAD(ks + 1);

        short8 af[4], bf[4];
        #pragma unroll
        for (int fr = 0; fr < 4; fr++)
            af[fr] = *(const short8*)&As[buf][(wrow + fr * 16 + lo) * LDA + hi * 8];
        #pragma unroll
        for (int fc = 0; fc < 4; fc++)
            bf[fc] = *(const short8*)&Bs[buf][(wcol + fc * 16 + lo) * LDA + hi * 8];
        #pragma unroll
        for (int fr = 0; fr < 4; fr++)
            #pragma unroll
            for (int fc = 0; fc < 4; fc++)
                acc[fr][fc] = __builtin_amdgcn_mfma_f32_16x16x32_bf16(
                    af[fr], bf[fc], acc[fr][fc], 0, 0, 0);

        if (ks + 1 < NKS) WRITE(buf ^ 1);
        __syncthreads();
    }

    const size_t bOff = (size_t)b * NN * TTOT;
    #pragma unroll
    for (int fr = 0; fr < 4; fr++) {
        const int ib = m0 + wrow + fr * 16 + hi * 4;
        float sA[4], sS[4], sR[4], sD[4], sB[4];
        #pragma unroll
        for (int rr = 0; rr < 4; rr++) {
            const float* p = &scal[(ib + rr) * 5];
            sA[rr] = p[0]; sS[rr] = p[1]; sR[rr] = p[2]; sD[rr] = p[3]; sB[rr] = p[4];
        }
        #pragma unroll
        for (int fc = 0; fc < 4; fc++) {
            const int t = t0 + wcol + fc * 16 + lo;
            #pragma unroll
            for (int rr = 0; rr < 4; rr++) {
                const int i = ib + rr;
                if (i < NN) {
                    const size_t o = bOff + (size_t)i * TTOT + t;
                    const float x = (t > 0) ? hb[(size_t)i * TTOT + t - 1] : 0.f;
                    const float elec = acc[fr][fc][rr] - sR[rr] * x;
                    const float chem = (sA[rr] - x * sS[rr]) * fmaxf(x, 0.f);
                    const float mu = sD[rr] * (chem + elec + sB[rr] + input[o] - x) + x;
                    out[o] = mu;
                    out[BNT + o] = chem;
                    out[2 * BNT + o] = elec;
                }
            }
        }
    }
}

extern "C" void kernel_launch(void* const* d_in, const int* in_sizes, int n_in,
                              void* d_out, int out_size, void* d_ws, size_t ws_size,
                              hipStream_t stream) {
    const float* input  = (const float*)d_in[0];
    const float* hidden = (const float*)d_in[1];
    const float* sc     = (const float*)d_in[2];
    const float* se     = (const float*)d_in[3];
    const float* mc     = (const float*)d_in[4];
    const float* me     = (const float*)d_in[5];
    const float* E      = (const float*)d_in[6];
    const float* bias   = (const float*)d_in[7];
    const float* tau    = (const float*)d_in[8];
    float* out = (float*)d_out;

    ushort* Web  = (ushort*)d_ws;
    float*  scal = (float*)((char*)d_ws + OFF_SCAL);
    ushort* WebP = (ushort*)((char*)d_ws + OFF_WEBP);
    ushort* xP   = (ushort*)((char*)d_ws + OFF_XP);

    lic_prep<<<MP, 64, 0, stream>>>(sc, se, mc, me, E, bias, tau, Web, WebP, scal);

    if (ws_size >= WS_NEED) {
        lic_xpose<<<TB * 5 * 64, 256, 0, stream>>>(hidden, xP);
        lic_main<<<TB * 80, 256, 0, stream>>>(input, hidden, xP, WebP, scal, out);
    } else {
        lic_mfma_fb<<<TB * 96, 256, 0, stream>>>(input, hidden, Web, scal, out);
    }
}

// Round 5
// 214.199 us; speedup vs baseline: 3.7553x; 1.1271x over previous
//
#include <hip/hip_runtime.h>
#include <hip/hip_bf16.h>

#define NN 300
#define TB 16
#define TTOT 4096
#define KP 320            // padded K (10 x 32)
#define MPAD 320          // padded M for main path (10 x 32)
#define MP 384            // padded M for scal table / fallback
#define NKS 10
#define BNT ((size_t)TB * NN * TTOT)

typedef __attribute__((ext_vector_type(8))) short short8;
typedef __attribute__((ext_vector_type(4))) float f32x4;

static __device__ __forceinline__ ushort f2bf(float f) {
    __hip_bfloat16 h = __float2bfloat16(f);
    return *reinterpret_cast<ushort*>(&h);
}

// ws layout (bytes):
//   Web   @ 0        : 384*320*2   = 245760   (row-major, fallback path)
//   scal  @ 245760   : 384*5*4     = 7680
//   WebP  @ 253440   : 20*10*1024  = 204800   (fragment-packed)
//   xP    @ 458240   : 16*256*10*1024 = 41943040
#define OFF_SCAL 245760
#define OFF_WEBP 253440
#define OFF_XP   458240
#define WS_NEED  (OFF_XP + (size_t)TB * 256 * NKS * 1024)

// ---------------- prep: W_e (row-major + packed) + per-row scalars ----------------
__global__ __launch_bounds__(64) void lic_prep(
    const float* __restrict__ sc, const float* __restrict__ se,
    const float* __restrict__ mc, const float* __restrict__ me,
    const float* __restrict__ E,  const float* __restrict__ bias,
    const float* __restrict__ tau,
    ushort* __restrict__ Web, ushort* __restrict__ WebP,
    float* __restrict__ scal /* [MP][5] */) {
    const int i = blockIdx.x;       // 0..MP-1
    const int lane = threadIdx.x;
    float a = 0.f, s = 0.f, r = 0.f;
    for (int j = lane; j < KP; j += 64) {
        float we = 0.f;
        if (i < NN && j < NN) {
            float wc = sc[i * NN + j] * (mc[i * NN + j] * 0.01f);
            a += wc * E[i * NN + j];
            s += wc;
            we = se[i * NN + j] * ((me[i * NN + j] + me[j * NN + i]) * 0.01f);
            r += we;
        }
        const ushort bf = f2bf(we);
        Web[(size_t)i * KP + j] = bf;
        if (i < MPAD) {
            const int mb = i >> 4, ri = i & 15;
            const int kb = j >> 5, ko = (j >> 3) & 3, e = j & 7;
            WebP[((size_t)(mb * NKS + kb) * 64 + (ri + ko * 16)) * 8 + e] = bf;
        }
    }
    #pragma unroll
    for (int o = 32; o > 0; o >>= 1) {
        a += __shfl_down(a, o);
        s += __shfl_down(s, o);
        r += __shfl_down(r, o);
    }
    if (lane == 0) {
        float* p = &scal[i * 5];
        p[0] = a;
        p[1] = s;
        p[2] = r;
        p[3] = (i < NN) ? (0.01f / tau[i]) : 0.f;
        p[4] = (i < NN) ? bias[i] : 0.f;
    }
}

// ---------------- xpose: packed bf16 fragments of time-shifted hidden ----------------
// xP[b][tbg(256)][ks(10)][lane(64)][e(8)] ; elem = x[b][t=tbg*16+(l&15)][k=ks*32+(l>>4)*8+e]
__global__ __launch_bounds__(256) void lic_xpose(
    const float* __restrict__ hidden, ushort* __restrict__ xP) {
    __shared__ float xs[64][65];
    const int nwg = TB * 5 * 64;                 // 5120
    const int blk0 = blockIdx.x;
    const int blk = (blk0 % 8) * (nwg / 8) + blk0 / 8;   // XCD chunking (bijective)
    const int b  = blk / 320;
    const int r  = blk % 320;
    const int j0 = (r / 64) * 64;
    const int t0 = (r % 64) * 64;
    const int tid = threadIdx.x;
    const int lane = tid & 63;
    const int row  = tid >> 6;
    const int lo = lane & 15, hi = lane >> 4;

    const float* hb = hidden + (size_t)b * NN * TTOT;
    const int gt = t0 + lane;
    #pragma unroll
    for (int u = 0; u < 16; u++) {
        const int jj = row + u * 4;
        const int j = j0 + jj;
        float v = 0.f;
        if (j < NN && gt > 0) v = hb[(size_t)j * TTOT + gt - 1];
        xs[jj][lane] = v;
    }
    __syncthreads();

    ushort* xb = xP + ((size_t)b * 256 + (t0 >> 4) + row) * (NKS * 512);
    #pragma unroll
    for (int ksl = 0; ksl < 2; ksl++) {
        const int ksg = (j0 >> 5) + ksl;
        short8 v;
        #pragma unroll
        for (int e = 0; e < 8; e++)
            v[e] = (short)f2bf(xs[ksl * 32 + hi * 8 + e][row * 16 + lo]);
        *(short8*)&xb[(size_t)ksg * 512 + lane * 8] = v;
    }
}

// ---------------- main: swapped-operand MFMA GEMM (C^T), float4 epilogue ----------------
// wave tile: 64 t x 32 m. acc[fr(t)][fc(m)]; C layout: t=(l>>4)*4+reg, m=l&15.
__global__ __launch_bounds__(256) void lic_main(
    const float* __restrict__ input, const float* __restrict__ hidden,
    const ushort* __restrict__ xP, const ushort* __restrict__ WebP,
    const float* __restrict__ scal, float* __restrict__ out) {
    const int nwg = TB * 160;                    // 2560
    const int blk0 = blockIdx.x;
    const int blk = (blk0 % 8) * (nwg / 8) + blk0 / 8;   // XCD chunking (bijective)
    const int b   = blk / 160;
    const int r   = blk % 160;
    const int tch = r / 10;
    const int m0  = (r % 10) * 32;
    const int tid = threadIdx.x;
    const int l  = tid & 63;
    const int w  = tid >> 6;
    const int t0 = tch * 256 + w * 64;           // wave: t0..t0+63, m0..m0+31
    const int lo = l & 15, hi = l >> 4;

    f32x4 acc[4][2];
    #pragma unroll
    for (int fr = 0; fr < 4; fr++)
        #pragma unroll
        for (int fc = 0; fc < 2; fc++)
            acc[fr][fc] = (f32x4){0.f, 0.f, 0.f, 0.f};

    const ushort* Wp = WebP + (size_t)(m0 >> 4) * (NKS * 512) + l * 8;
    const ushort* Xp = xP + ((size_t)b * 256 + (t0 >> 4)) * (NKS * 512) + l * 8;

    short8 xbuf[2][4], wbuf[2][2];
    #pragma unroll
    for (int fr = 0; fr < 4; fr++)
        xbuf[0][fr] = *(const short8*)&Xp[(size_t)fr * (NKS * 512)];
    #pragma unroll
    for (int fc = 0; fc < 2; fc++)
        wbuf[0][fc] = *(const short8*)&Wp[(size_t)fc * (NKS * 512)];

    #pragma unroll
    for (int ks = 0; ks < NKS; ks++) {
        const int c = ks & 1, n = c ^ 1;
        if (ks + 1 < NKS) {
            #pragma unroll
            for (int fr = 0; fr < 4; fr++)
                xbuf[n][fr] = *(const short8*)&Xp[(size_t)fr * (NKS * 512) + (ks + 1) * 512];
            #pragma unroll
            for (int fc = 0; fc < 2; fc++)
                wbuf[n][fc] = *(const short8*)&Wp[(size_t)fc * (NKS * 512) + (ks + 1) * 512];
        }
        #pragma unroll
        for (int fr = 0; fr < 4; fr++)
            #pragma unroll
            for (int fc = 0; fc < 2; fc++)
                acc[fr][fc] = __builtin_amdgcn_mfma_f32_16x16x32_bf16(
                    xbuf[c][fr], wbuf[c][fc], acc[fr][fc], 0, 0, 0);
    }

    // ---- epilogue: per fragment, lane owns 4 consecutive t at one row i ----
    const size_t bOff = (size_t)b * NN * TTOT;
    const float* hb = hidden + bOff;
    const float* ib_in = input + bOff;
    #pragma unroll
    for (int fc = 0; fc < 2; fc++) {
        const int i = m0 + fc * 16 + lo;
        const bool ok = (i < NN);
        const float* p = &scal[i * 5];
        const float sA = p[0], sS = p[1], sR = p[2], sD = p[3], sB = p[4];
        #pragma unroll
        for (int fr = 0; fr < 4; fr++) {
            const int tb = t0 + fr * 16 + hi * 4;
            const size_t o = bOff + (size_t)i * TTOT + tb;
            const size_t ho = (size_t)i * TTOT + tb;
            f32x4 hv = ok ? *(const f32x4*)&hb[ho] : (f32x4){0.f,0.f,0.f,0.f};
            f32x4 inv = ok ? *(const f32x4*)&ib_in[ho] : (f32x4){0.f,0.f,0.f,0.f};
            const float xm1 = (ok && tb > 0) ? hb[ho - 1] : 0.f;
            float xv[4] = {xm1, hv[0], hv[1], hv[2]};
            f32x4 vmu, vch, vel;
            #pragma unroll
            for (int rr = 0; rr < 4; rr++) {
                const float x = xv[rr];
                const float elec = acc[fr][fc][rr] - sR * x;
                const float chem = (sA - x * sS) * fmaxf(x, 0.f);
                vel[rr] = elec;
                vch[rr] = chem;
                vmu[rr] = sD * (chem + elec + sB + inv[rr] - x) + x;
            }
            if (ok) {
                *(f32x4*)&out[o] = vmu;
                *(f32x4*)&out[BNT + o] = vch;
                *(f32x4*)&out[2 * BNT + o] = vel;
            }
        }
    }
}

// ================= fallback path (validated R1 kernel, row-major Web) =================
#define BM 128
#define BTT 128
#define BK 32
#define LDA 40

__global__ __launch_bounds__(256) void lic_mfma_fb(
    const float* __restrict__ input, const float* __restrict__ hidden,
    const ushort* __restrict__ Web, const float* __restrict__ scal,
    float* __restrict__ out) {
    __shared__ ushort As[2][BM * LDA];
    __shared__ ushort Bs[2][BTT * LDA];

    const int blk = blockIdx.x;
    const int b  = blk / 96;
    const int mt = (blk % 96) / 32;
    const int tt = blk % 32;
    const int m0 = mt * BM;
    const int t0 = tt * BTT;
    const int tid = threadIdx.x;
    const int l   = tid & 63;
    const int w   = tid >> 6;
    const int wrow = (w >> 1) * 64;
    const int wcol = (w & 1) * 64;
    const int lo = l & 15, hi = l >> 4;

    const float* hb = hidden + (size_t)b * NN * TTOT;

    f32x4 acc[4][4];
    #pragma unroll
    for (int fr = 0; fr < 4; fr++)
        #pragma unroll
        for (int fc = 0; fc < 4; fc++)
            acc[fr][fc] = (f32x4){0.f, 0.f, 0.f, 0.f};

    short8 aReg[2];
    float  bReg[16];
    const int tl = tid & 127;
    const int jg = (tid >> 7) * 16;
    const int gt = t0 + tl;

    auto LOAD = [&](int ks) {
        const int k0 = ks * BK;
        #pragma unroll
        for (int u = 0; u < 2; u++) {
            const int c = tid + u * 256;
            const int row = c >> 2, ko = (c & 3) * 8;
            aReg[u] = *(const short8*)&Web[(size_t)(m0 + row) * KP + k0 + ko];
        }
        #pragma unroll
        for (int e = 0; e < 16; e++) {
            const int j = k0 + jg + e;
            float v = 0.f;
            if (j < NN && gt > 0) v = hb[(size_t)j * TTOT + gt - 1];
            bReg[e] = v;
        }
    };
    auto WRITE = [&](int buf) {
        #pragma unroll
        for (int u = 0; u < 2; u++) {
            const int c = tid + u * 256;
            const int row = c >> 2, ko = (c & 3) * 8;
            *(short8*)&As[buf][row * LDA + ko] = aReg[u];
        }
        short8 w0, w1;
        #pragma unroll
        for (int e = 0; e < 8; e++) {
            w0[e] = (short)f2bf(bReg[e]);
            w1[e] = (short)f2bf(bReg[e + 8]);
        }
        *(short8*)&Bs[buf][tl * LDA + jg]     = w0;
        *(short8*)&Bs[buf][tl * LDA + jg + 8] = w1;
    };

    LOAD(0); WRITE(0);
    __syncthreads();

    for (int ks = 0; ks < NKS; ks++) {
        const int buf = ks & 1;
        if (ks + 1 < NKS) LOAD(ks + 1);

        short8 af[4], bf[4];
        #pragma unroll
        for (int fr = 0; fr < 4; fr++)
            af[fr] = *(const short8*)&As[buf][(wrow + fr * 16 + lo) * LDA + hi * 8];
        #pragma unroll
        for (int fc = 0; fc < 4; fc++)
            bf[fc] = *(const short8*)&Bs[buf][(wcol + fc * 16 + lo) * LDA + hi * 8];
        #pragma unroll
        for (int fr = 0; fr < 4; fr++)
            #pragma unroll
            for (int fc = 0; fc < 4; fc++)
                acc[fr][fc] = __builtin_amdgcn_mfma_f32_16x16x32_bf16(
                    af[fr], bf[fc], acc[fr][fc], 0, 0, 0);

        if (ks + 1 < NKS) WRITE(buf ^ 1);
        __syncthreads();
    }

    const size_t bOff = (size_t)b * NN * TTOT;
    #pragma unroll
    for (int fr = 0; fr < 4; fr++) {
        const int ib = m0 + wrow + fr * 16 + hi * 4;
        float sA[4], sS[4], sR[4], sD[4], sB[4];
        #pragma unroll
        for (int rr = 0; rr < 4; rr++) {
            const float* p = &scal[(ib + rr) * 5];
            sA[rr] = p[0]; sS[rr] = p[1]; sR[rr] = p[2]; sD[rr] = p[3]; sB[rr] = p[4];
        }
        #pragma unroll
        for (int fc = 0; fc < 4; fc++) {
            const int t = t0 + wcol + fc * 16 + lo;
            #pragma unroll
            for (int rr = 0; rr < 4; rr++) {
                const int i = ib + rr;
                if (i < NN) {
                    const size_t o = bOff + (size_t)i * TTOT + t;
                    const float x = (t > 0) ? hb[(size_t)i * TTOT + t - 1] : 0.f;
                    const float elec = acc[fr][fc][rr] - sR[rr] * x;
                    const float chem = (sA[rr] - x * sS[rr]) * fmaxf(x, 0.f);
                    const float mu = sD[rr] * (chem + elec + sB[rr] + input[o] - x) + x;
                    out[o] = mu;
                    out[BNT + o] = chem;
                    out[2 * BNT + o] = elec;
                }
            }
        }
    }
}

extern "C" void kernel_launch(void* const* d_in, const int* in_sizes, int n_in,
                              void* d_out, int out_size, void* d_ws, size_t ws_size,
                              hipStream_t stream) {
    const float* input  = (const float*)d_in[0];
    const float* hidden = (const float*)d_in[1];
    const float* sc     = (const float*)d_in[2];
    const float* se     = (const float*)d_in[3];
    const float* mc     = (const float*)d_in[4];
    const float* me     = (const float*)d_in[5];
    const float* E      = (const float*)d_in[6];
    const float* bias   = (const float*)d_in[7];
    const float* tau    = (const float*)d_in[8];
    float* out = (float*)d_out;

    ushort* Web  = (ushort*)d_ws;
    float*  scal = (float*)((char*)d_ws + OFF_SCAL);
    ushort* WebP = (ushort*)((char*)d_ws + OFF_WEBP);
    ushort* xP   = (ushort*)((char*)d_ws + OFF_XP);

    lic_prep<<<MP, 64, 0, stream>>>(sc, se, mc, me, E, bias, tau, Web, WebP, scal);

    if (ws_size >= WS_NEED) {
        lic_xpose<<<TB * 5 * 64, 256, 0, stream>>>(hidden, xP);
        lic_main<<<TB * 160, 256, 0, stream>>>(input, hidden, xP, WebP, scal, out);
    } else {
        lic_mfma_fb<<<TB * 96, 256, 0, stream>>>(input, hidden, Web, scal, out);
    }
}

// Round 6
// 156.804 us; speedup vs baseline: 5.1299x; 1.3660x over previous
//
#include <hip/hip_runtime.h>
#include <hip/hip_bf16.h>

#define NN 300
#define TB 16
#define TTOT 4096
#define MPAD 320            // padded M/K (20 x 16 / 10 x 32)
#define NKS 10
#define TC 32               // t-chunk per block
#define NTC (TTOT / TC)     // 128
#define LDX 328             // LDS row stride in ushort (656 B)
#define BNT ((size_t)TB * NN * TTOT)

typedef __attribute__((ext_vector_type(8))) short short8;
typedef __attribute__((ext_vector_type(4))) float f32x4;

static __device__ __forceinline__ ushort f2bf(float f) {
    __hip_bfloat16 h = __float2bfloat16(f);
    return *reinterpret_cast<ushort*>(&h);
}
static __device__ __forceinline__ float bf2f(ushort u) {
    unsigned v = ((unsigned)u) << 16;
    return __uint_as_float(v);
}

// ws layout: WebP @0 : 20*10*512 ushorts = 204800 B ; scal @204800 : 320*5*4 = 6400 B
#define OFF_SCAL 204800

// ---------------- prep: packed bf16 W_e fragments + per-row scalars ----------------
// WebP[mb(20)][ks(10)][lane(64)][e(8)] ; elem = W_e[i = mb*16 + (l&15)][k = ks*32 + (l>>4)*8 + e]
__global__ __launch_bounds__(64) void lic_prep(
    const float* __restrict__ sc, const float* __restrict__ se,
    const float* __restrict__ mc, const float* __restrict__ me,
    const float* __restrict__ E,  const float* __restrict__ bias,
    const float* __restrict__ tau,
    ushort* __restrict__ WebP, float* __restrict__ scal /* [320][5] */) {
    const int i = blockIdx.x;       // 0..319
    const int lane = threadIdx.x;
    float a = 0.f, s = 0.f, r = 0.f;
    for (int j = lane; j < MPAD; j += 64) {
        float we = 0.f;
        if (i < NN && j < NN) {
            float wc = sc[i * NN + j] * (mc[i * NN + j] * 0.01f);
            a += wc * E[i * NN + j];
            s += wc;
            we = se[i * NN + j] * ((me[i * NN + j] + me[j * NN + i]) * 0.01f);
            r += we;
        }
        const int mb = i >> 4, ri = i & 15;
        const int kb = j >> 5, ko = (j >> 3) & 3, e = j & 7;
        WebP[((size_t)(mb * NKS + kb) * 64 + (ri + ko * 16)) * 8 + e] = f2bf(we);
    }
    #pragma unroll
    for (int o = 32; o > 0; o >>= 1) {
        a += __shfl_down(a, o);
        s += __shfl_down(s, o);
        r += __shfl_down(r, o);
    }
    if (lane == 0) {
        float* p = &scal[i * 5];
        p[0] = a;
        p[1] = s;
        p[2] = r;
        p[3] = (i < NN) ? (0.01f / tau[i]) : 0.f;
        p[4] = (i < NN) ? bias[i] : 0.f;
    }
}

// ---------------- fused: stage x tile -> full-K MFMA GEMM -> fused epilogue ----------------
// block = (b, 32-t chunk); 4 waves, wave tile 32t x 80m; one barrier total.
__global__ __launch_bounds__(256, 3) void lic_fused(
    const float* __restrict__ input, const float* __restrict__ hidden,
    const ushort* __restrict__ WebP, const float* __restrict__ scal,
    float* __restrict__ out) {
    __shared__ ushort xs[TC][LDX];          // x (time-shifted, bf16), rows t, cols j

    const int nwg = TB * NTC;               // 2048
    const int blk0 = blockIdx.x;
    const int blk = (blk0 & 7) * (nwg / 8) + (blk0 >> 3);   // XCD chunking (bijective)
    const int b  = blk / NTC;
    const int tc = blk % NTC;
    const int t0 = tc * TC;
    const int tid = threadIdx.x;
    const size_t bOff = (size_t)b * NN * TTOT;
    const float* hb = hidden + bOff;

    // ---- stage x[b, 0..319, t0..t0+31] into LDS (bf16, shift baked in) ----
    {
        const int t4 = tid & 7;             // float4 slot within 32-t row
        const int jl = tid >> 3;            // 32 j rows per iteration
        #pragma unroll
        for (int it = 0; it < 10; ++it) {
            const int j = jl + it * 32;     // 0..319
            f32x4 hv = (f32x4){0.f, 0.f, 0.f, 0.f};
            float x0 = 0.f;
            if (j < NN) {
                const float* hp = hb + (size_t)j * TTOT + t0 + t4 * 4;
                hv = __builtin_nontemporal_load((const f32x4*)hp);
                if (t4 == 0 && t0 > 0) x0 = hp[-1];
            }
            if (t4 == 0) xs[0][j] = f2bf(x0);
            #pragma unroll
            for (int r = 0; r < 3; ++r) xs[t4 * 4 + r + 1][j] = f2bf(hv[r]);
            if (t4 < 7) xs[t4 * 4 + 4][j] = f2bf(hv[3]);
        }
    }
    __syncthreads();

    const int l  = tid & 63;
    const int w  = tid >> 6;                // wave 0..3 -> m0 = w*80
    const int lo = l & 15, hi = l >> 4;

    f32x4 acc[2][5];
    #pragma unroll
    for (int fr = 0; fr < 2; ++fr)
        #pragma unroll
        for (int fc = 0; fc < 5; ++fc)
            acc[fr][fc] = (f32x4){0.f, 0.f, 0.f, 0.f};

    // W fragments: WebP chunk (mb = w*5+fc, ks), lane-linear
    const ushort* WpBase = WebP + ((size_t)(w * 5) * NKS) * 512 + l * 8;

    short8 wbuf[2][5];
    #pragma unroll
    for (int fc = 0; fc < 5; ++fc)
        wbuf[0][fc] = *(const short8*)(WpBase + (size_t)(fc * NKS) * 512);

    #pragma unroll
    for (int ks = 0; ks < NKS; ++ks) {
        const int c = ks & 1, n = c ^ 1;
        if (ks + 1 < NKS) {
            #pragma unroll
            for (int fc = 0; fc < 5; ++fc)
                wbuf[n][fc] = *(const short8*)(WpBase + (size_t)(fc * NKS + ks + 1) * 512);
        }
        short8 xf[2];
        #pragma unroll
        for (int fr = 0; fr < 2; ++fr)
            xf[fr] = *(const short8*)&xs[fr * 16 + lo][ks * 32 + hi * 8];
        #pragma unroll
        for (int fr = 0; fr < 2; ++fr)
            #pragma unroll
            for (int fc = 0; fc < 5; ++fc)
                acc[fr][fc] = __builtin_amdgcn_mfma_f32_16x16x32_bf16(
                    xf[fr], wbuf[c][fc], acc[fr][fc], 0, 0, 0);
    }

    // ---- epilogue: C^T layout (t = fr*16 + hi*4 + rr, i = w*80 + fc*16 + lo) ----
    #pragma unroll
    for (int fc = 0; fc < 5; ++fc) {
        const int i = w * 80 + fc * 16 + lo;
        const bool ok = (i < NN);
        const float* p = &scal[i * 5];
        const float sA = p[0], sS = p[1], sR = p[2], sD = p[3], sB = p[4];
        #pragma unroll
        for (int fr = 0; fr < 2; ++fr) {
            const int tb = fr * 16 + hi * 4;
            const size_t o = bOff + (size_t)i * TTOT + t0 + tb;
            f32x4 inv = (f32x4){0.f, 0.f, 0.f, 0.f};
            if (ok) inv = __builtin_nontemporal_load((const f32x4*)&input[o]);
            float xv[4];
            #pragma unroll
            for (int rr = 0; rr < 4; ++rr) xv[rr] = bf2f(xs[tb + rr][i]);
            f32x4 vmu, vch, vel;
            #pragma unroll
            for (int rr = 0; rr < 4; ++rr) {
                const float x = xv[rr];
                const float elec = acc[fr][fc][rr] - sR * x;
                const float chem = (sA - x * sS) * fmaxf(x, 0.f);
                vel[rr] = elec;
                vch[rr] = chem;
                vmu[rr] = sD * (chem + elec + sB + inv[rr] - x) + x;
            }
            if (ok) {
                __builtin_nontemporal_store(vmu, (f32x4*)&out[o]);
                __builtin_nontemporal_store(vch, (f32x4*)&out[BNT + o]);
                __builtin_nontemporal_store(vel, (f32x4*)&out[2 * BNT + o]);
            }
        }
    }
}

extern "C" void kernel_launch(void* const* d_in, const int* in_sizes, int n_in,
                              void* d_out, int out_size, void* d_ws, size_t ws_size,
                              hipStream_t stream) {
    const float* input  = (const float*)d_in[0];
    const float* hidden = (const float*)d_in[1];
    const float* sc     = (const float*)d_in[2];
    const float* se     = (const float*)d_in[3];
    const float* mc     = (const float*)d_in[4];
    const float* me     = (const float*)d_in[5];
    const float* E      = (const float*)d_in[6];
    const float* bias   = (const float*)d_in[7];
    const float* tau    = (const float*)d_in[8];
    float* out = (float*)d_out;

    ushort* WebP = (ushort*)d_ws;
    float*  scal = (float*)((char*)d_ws + OFF_SCAL);

    lic_prep<<<MPAD, 64, 0, stream>>>(sc, se, mc, me, E, bias, tau, WebP, scal);
    lic_fused<<<TB * NTC, 256, 0, stream>>>(input, hidden, WebP, scal, out);
}

// Round 7
// 97.166 us; speedup vs baseline: 8.2784x; 1.6138x over previous
//
#include <hip/hip_runtime.h>
#include <hip/hip_bf16.h>

#define NN 300
#define TB 16
#define TTOT 4096
#define MPAD 320            // padded M/K (20 x 16 / 10 x 32)
#define NKS 10
#define TC 32               // t-chunk per block
#define NTC (TTOT / TC)     // 128
#define LDX 328             // LDS row stride in ushort (656 B)
#define BNT ((size_t)TB * NN * TTOT)

typedef __attribute__((ext_vector_type(8))) short short8;
typedef __attribute__((ext_vector_type(4))) float f32x4;

static __device__ __forceinline__ ushort f2bf(float f) {
    __hip_bfloat16 h = __float2bfloat16(f);
    return *reinterpret_cast<ushort*>(&h);
}
static __device__ __forceinline__ float bf2f(ushort u) {
    unsigned v = ((unsigned)u) << 16;
    return __uint_as_float(v);
}

// ws layout: WebP @0 : 20*10*512 ushorts = 204800 B ; scal @204800 : 320*5*4 = 6400 B
#define OFF_SCAL 204800

// ---------------- prep: packed bf16 W_e fragments + per-row scalars ----------------
// WebP[mb(20)][ks(10)][lane(64)][e(8)] ; elem = W_e[i = mb*16 + (l&15)][k = ks*32 + (l>>4)*8 + e]
__global__ __launch_bounds__(64) void lic_prep(
    const float* __restrict__ sc, const float* __restrict__ se,
    const float* __restrict__ mc, const float* __restrict__ me,
    const float* __restrict__ E,  const float* __restrict__ bias,
    const float* __restrict__ tau,
    ushort* __restrict__ WebP, float* __restrict__ scal /* [320][5] */) {
    const int i = blockIdx.x;       // 0..319
    const int lane = threadIdx.x;
    float a = 0.f, s = 0.f, r = 0.f;
    for (int j = lane; j < MPAD; j += 64) {
        float we = 0.f;
        if (i < NN && j < NN) {
            float wc = sc[i * NN + j] * (mc[i * NN + j] * 0.01f);
            a += wc * E[i * NN + j];
            s += wc;
            we = se[i * NN + j] * ((me[i * NN + j] + me[j * NN + i]) * 0.01f);
            r += we;
        }
        const int mb = i >> 4, ri = i & 15;
        const int kb = j >> 5, ko = (j >> 3) & 3, e = j & 7;
        WebP[((size_t)(mb * NKS + kb) * 64 + (ri + ko * 16)) * 8 + e] = f2bf(we);
    }
    #pragma unroll
    for (int o = 32; o > 0; o >>= 1) {
        a += __shfl_down(a, o);
        s += __shfl_down(s, o);
        r += __shfl_down(r, o);
    }
    if (lane == 0) {
        float* p = &scal[i * 5];
        p[0] = a;
        p[1] = s;
        p[2] = r;
        p[3] = (i < NN) ? (0.01f / tau[i]) : 0.f;
        p[4] = (i < NN) ? bias[i] : 0.f;
    }
}

// ---------------- fused: stage x tile -> 5 pipelined fc-passes (GEMM+epilogue) ----------------
__global__ __launch_bounds__(256, 4) void lic_fused(
    const float* __restrict__ input, const float* __restrict__ hidden,
    const ushort* __restrict__ WebP, const float* __restrict__ scal,
    float* __restrict__ out) {
    __shared__ ushort xs[TC][LDX];          // x (time-shifted, bf16), rows t, cols j

    const int nwg = TB * NTC;               // 2048
    const int blk0 = blockIdx.x;
    const int blk = (blk0 & 7) * (nwg / 8) + (blk0 >> 3);   // XCD chunking (bijective)
    const int b  = blk / NTC;
    const int tc = blk % NTC;
    const int t0 = tc * TC;
    const int tid = threadIdx.x;
    const size_t bOff = (size_t)b * NN * TTOT;
    const float* hb = hidden + bOff;

    // ---- stage x[b, 0..319, t0..t0+31] into LDS (bf16, shift baked in) ----
    {
        const int t4 = tid & 7;             // float4 slot within 32-t row
        const int jl = tid >> 3;            // 32 j rows per iteration
        #pragma unroll
        for (int it = 0; it < 10; ++it) {
            const int j = jl + it * 32;     // 0..319
            f32x4 hv = (f32x4){0.f, 0.f, 0.f, 0.f};
            float x0 = 0.f;
            if (j < NN) {
                const float* hp = hb + (size_t)j * TTOT + t0 + t4 * 4;
                hv = *(const f32x4*)hp;
                if (t4 == 0 && t0 > 0) x0 = hp[-1];
            }
            if (t4 == 0) xs[0][j] = f2bf(x0);
            #pragma unroll
            for (int r = 0; r < 3; ++r) xs[t4 * 4 + r + 1][j] = f2bf(hv[r]);
            if (t4 < 7) xs[t4 * 4 + 4][j] = f2bf(hv[3]);
        }
    }
    __syncthreads();

    const int l  = tid & 63;
    const int w  = tid >> 6;                // wave 0..3 -> i base = w*80
    const int lo = l & 15, hi = l >> 4;
    const int iBase = w * 80;

    const f32x4 vzero = (f32x4){0.f, 0.f, 0.f, 0.f};

    // input prefetch (double-buffered across fc passes)
    f32x4 inpA[2], inpB[2];
    auto loadInp = [&](int fc, f32x4* dst) {
        const int i = iBase + fc * 16 + lo;
        if (i < NN) {
            const float* ip = input + bOff + (size_t)i * TTOT + t0 + hi * 4;
            dst[0] = *(const f32x4*)ip;
            dst[1] = *(const f32x4*)(ip + 16);
        } else {
            dst[0] = vzero; dst[1] = vzero;
        }
    };
    loadInp(0, inpA);

    #pragma unroll
    for (int fc = 0; fc < 5; ++fc) {
        const f32x4* curInp = (fc & 1) ? inpB : inpA;
        f32x4*       nxtInp = (fc & 1) ? inpA : inpB;
        if (fc + 1 < 5) loadInp(fc + 1, nxtInp);

        const int i = iBase + fc * 16 + lo;
        // scalar row constants (issued early; L2-hot)
        const float* p = &scal[i * 5];
        const float sA = p[0], sS = p[1], sR = p[2], sD = p[3], sB = p[4];

        // ---- GEMM pass: 10 ks x 2 MFMA, acc = 8 AGPRs ----
        f32x4 acc0 = vzero, acc1 = vzero;
        const ushort* Wp = WebP + ((size_t)((iBase >> 4) + fc) * NKS) * 512 + l * 8;
        #pragma unroll
        for (int ks = 0; ks < NKS; ++ks) {
            const short8 wf  = *(const short8*)(Wp + (size_t)ks * 512);
            const short8 xf0 = *(const short8*)&xs[lo][ks * 32 + hi * 8];
            const short8 xf1 = *(const short8*)&xs[16 + lo][ks * 32 + hi * 8];
            acc0 = __builtin_amdgcn_mfma_f32_16x16x32_bf16(xf0, wf, acc0, 0, 0, 0);
            acc1 = __builtin_amdgcn_mfma_f32_16x16x32_bf16(xf1, wf, acc1, 0, 0, 0);
        }

        // ---- epilogue for this fc: C^T layout (t = fr*16 + hi*4 + rr, col i) ----
        const bool ok = (i < NN);
        #pragma unroll
        for (int fr = 0; fr < 2; ++fr) {
            const f32x4 accv = fr ? acc1 : acc0;
            const int tb = fr * 16 + hi * 4;
            const size_t o = bOff + (size_t)i * TTOT + t0 + tb;
            const f32x4 inv = curInp[fr];
            f32x4 vmu, vch, vel;
            #pragma unroll
            for (int rr = 0; rr < 4; ++rr) {
                const float x = bf2f(xs[tb + rr][i]);
                const float elec = accv[rr] - sR * x;
                const float chem = (sA - x * sS) * fmaxf(x, 0.f);
                vel[rr] = elec;
                vch[rr] = chem;
                vmu[rr] = sD * (chem + elec + sB + inv[rr] - x) + x;
            }
            if (ok) {
                __builtin_nontemporal_store(vmu, (f32x4*)&out[o]);
                __builtin_nontemporal_store(vch, (f32x4*)&out[BNT + o]);
                __builtin_nontemporal_store(vel, (f32x4*)&out[2 * BNT + o]);
            }
        }
    }
}

extern "C" void kernel_launch(void* const* d_in, const int* in_sizes, int n_in,
                              void* d_out, int out_size, void* d_ws, size_t ws_size,
                              hipStream_t stream) {
    const float* input  = (const float*)d_in[0];
    const float* hidden = (const float*)d_in[1];
    const float* sc     = (const float*)d_in[2];
    const float* se     = (const float*)d_in[3];
    const float* mc     = (const float*)d_in[4];
    const float* me     = (const float*)d_in[5];
    const float* E      = (const float*)d_in[6];
    const float* bias   = (const float*)d_in[7];
    const float* tau    = (const float*)d_in[8];
    float* out = (float*)d_out;

    ushort* WebP = (ushort*)d_ws;
    float*  scal = (float*)((char*)d_ws + OFF_SCAL);

    lic_prep<<<MPAD, 64, 0, stream>>>(sc, se, mc, me, E, bias, tau, WebP, scal);
    lic_fused<<<TB * NTC, 256, 0, stream>>>(input, hidden, WebP, scal, out);
}

// Round 8
// 72.592 us; speedup vs baseline: 11.0809x; 1.3385x over previous
//
#include <hip/hip_runtime.h>
#include <hip/hip_bf16.h>

#define NN 300
#define TB 16
#define TTOT 4096
#define MPAD 320            // padded M/K (20 x 16 / 10 x 32)
#define NKS 10
#define TC 32               // t-chunk per block
#define NTC (TTOT / TC)     // 128
#define LDX 328             // LDS row stride in ushort (656 B, 16B-aligned rows)
#define FBS 36              // flush-buffer row stride in dwords (144 B, 16B-aligned)
#define BNT ((size_t)TB * NN * TTOT)

typedef __attribute__((ext_vector_type(8))) short short8;
typedef __attribute__((ext_vector_type(4))) float f32x4;

static __device__ __forceinline__ ushort f2bf(float f) {
    __hip_bfloat16 h = __float2bfloat16(f);
    return *reinterpret_cast<ushort*>(&h);
}
static __device__ __forceinline__ float bf2f(ushort u) {
    unsigned v = ((unsigned)u) << 16;
    return __uint_as_float(v);
}

// ws layout: WebP @0 : 20*10*512 ushorts = 204800 B ; scal @204800 : 320*5*4 = 6400 B
#define OFF_SCAL 204800

// ---------------- prep: packed bf16 W_e fragments + per-row scalars ----------------
// WebP[mb(20)][ks(10)][lane(64)][e(8)] ; elem = W_e[i = mb*16 + (l&15)][k = ks*32 + (l>>4)*8 + e]
__global__ __launch_bounds__(64) void lic_prep(
    const float* __restrict__ sc, const float* __restrict__ se,
    const float* __restrict__ mc, const float* __restrict__ me,
    const float* __restrict__ E,  const float* __restrict__ bias,
    const float* __restrict__ tau,
    ushort* __restrict__ WebP, float* __restrict__ scal /* [320][5] */) {
    const int i = blockIdx.x;       // 0..319
    const int lane = threadIdx.x;
    float a = 0.f, s = 0.f, r = 0.f;
    for (int j = lane; j < MPAD; j += 64) {
        float we = 0.f;
        if (i < NN && j < NN) {
            float wc = sc[i * NN + j] * (mc[i * NN + j] * 0.01f);
            a += wc * E[i * NN + j];
            s += wc;
            we = se[i * NN + j] * ((me[i * NN + j] + me[j * NN + i]) * 0.01f);
            r += we;
        }
        const int mb = i >> 4, ri = i & 15;
        const int kb = j >> 5, ko = (j >> 3) & 3, e = j & 7;
        WebP[((size_t)(mb * NKS + kb) * 64 + (ri + ko * 16)) * 8 + e] = f2bf(we);
    }
    #pragma unroll
    for (int o = 32; o > 0; o >>= 1) {
        a += __shfl_down(a, o);
        s += __shfl_down(s, o);
        r += __shfl_down(r, o);
    }
    if (lane == 0) {
        float* p = &scal[i * 5];
        p[0] = a;
        p[1] = s;
        p[2] = r;
        p[3] = (i < NN) ? (0.01f / tau[i]) : 0.f;
        p[4] = (i < NN) ? bias[i] : 0.f;
    }
}

// ---------------- fused: stage x tile -> 5 pipelined fc-passes -> full-line flush ----------------
__global__ __launch_bounds__(256, 4) void lic_fused(
    const float* __restrict__ input, const float* __restrict__ hidden,
    const ushort* __restrict__ WebP, const float* __restrict__ scal,
    float* __restrict__ out) {
    __shared__ ushort xs[TC][LDX];          // x (time-shifted, bf16), rows t, cols j
    __shared__ float fbuf[4][16 * FBS];     // per-wave store-staging (2304 B each)

    const int nwg = TB * NTC;               // 2048
    const int blk0 = blockIdx.x;
    const int blk = (blk0 & 7) * (nwg / 8) + (blk0 >> 3);   // XCD chunking (bijective)
    const int b  = blk / NTC;
    const int tc = blk % NTC;
    const int t0 = tc * TC;
    const int tid = threadIdx.x;
    const size_t bOff = (size_t)b * NN * TTOT;
    const float* hb = hidden + bOff;

    // ---- stage x[b, 0..319, t0..t0+31] into LDS (bf16, shift baked in) ----
    {
        const int t4 = tid & 7;             // float4 slot within 32-t row
        const int jl = tid >> 3;            // 32 j rows per iteration
        #pragma unroll
        for (int it = 0; it < 10; ++it) {
            const int j = jl + it * 32;     // 0..319
            f32x4 hv = (f32x4){0.f, 0.f, 0.f, 0.f};
            float x0 = 0.f;
            if (j < NN) {
                const float* hp = hb + (size_t)j * TTOT + t0 + t4 * 4;
                hv = *(const f32x4*)hp;
                if (t4 == 0 && t0 > 0) x0 = hp[-1];
            }
            if (t4 == 0) xs[0][j] = f2bf(x0);
            #pragma unroll
            for (int r = 0; r < 3; ++r) xs[t4 * 4 + r + 1][j] = f2bf(hv[r]);
            if (t4 < 7) xs[t4 * 4 + 4][j] = f2bf(hv[3]);
        }
    }
    __syncthreads();

    const int l  = tid & 63;
    const int w  = tid >> 6;                // wave 0..3 -> i base = w*80
    const int lo = l & 15, hi = l >> 4;
    const int iBase = w * 80;
    float* fb = &fbuf[w][0];

    // flush-read/store lane mapping: 8 rows x 128 B contiguous per instr
    const int rrow = l >> 3;                // 0..7
    const int rcol = (l & 7) * 4;           // 0,4,...,28

    const f32x4 vzero = (f32x4){0.f, 0.f, 0.f, 0.f};

    // input prefetch (double-buffered across fc passes)
    f32x4 inpA[2], inpB[2];
    auto loadInp = [&](int fc, f32x4* dst) {
        const int i = iBase + fc * 16 + lo;
        if (i < NN) {
            const float* ip = input + bOff + (size_t)i * TTOT + t0 + hi * 4;
            dst[0] = *(const f32x4*)ip;
            dst[1] = *(const f32x4*)(ip + 16);
        } else {
            dst[0] = vzero; dst[1] = vzero;
        }
    };
    loadInp(0, inpA);

    #pragma unroll
    for (int fc = 0; fc < 5; ++fc) {
        const f32x4* curInp = (fc & 1) ? inpB : inpA;
        f32x4*       nxtInp = (fc & 1) ? inpA : inpB;
        if (fc + 1 < 5) loadInp(fc + 1, nxtInp);

        const int i = iBase + fc * 16 + lo;
        const float* p = &scal[i * 5];
        const float sA = p[0], sS = p[1], sR = p[2], sD = p[3], sB = p[4];

        // ---- GEMM pass: 10 ks x 2 MFMA, acc = 8 AGPRs ----
        f32x4 acc0 = vzero, acc1 = vzero;
        const ushort* Wp = WebP + ((size_t)((iBase >> 4) + fc) * NKS) * 512 + l * 8;
        #pragma unroll
        for (int ks = 0; ks < NKS; ++ks) {
            const short8 wf  = *(const short8*)(Wp + (size_t)ks * 512);
            const short8 xf0 = *(const short8*)&xs[lo][ks * 32 + hi * 8];
            const short8 xf1 = *(const short8*)&xs[16 + lo][ks * 32 + hi * 8];
            acc0 = __builtin_amdgcn_mfma_f32_16x16x32_bf16(xf0, wf, acc0, 0, 0, 0);
            acc1 = __builtin_amdgcn_mfma_f32_16x16x32_bf16(xf1, wf, acc1, 0, 0, 0);
        }

        // ---- epilogue compute: C^T layout (t = fr*16 + hi*4 + rr, col i) ----
        f32x4 vmu[2], vch[2], vel[2];
        #pragma unroll
        for (int fr = 0; fr < 2; ++fr) {
            const f32x4 accv = fr ? acc1 : acc0;
            const int tb = fr * 16 + hi * 4;
            const f32x4 inv = curInp[fr];
            #pragma unroll
            for (int rr = 0; rr < 4; ++rr) {
                const float x = bf2f(xs[tb + rr][i]);
                const float elec = accv[rr] - sR * x;
                const float chem = (sA - x * sS) * fmaxf(x, 0.f);
                vel[fr][rr] = elec;
                vch[fr][rr] = chem;
                vmu[fr][rr] = sD * (chem + elec + sB + inv[rr] - x) + x;
            }
        }

        // ---- flush: LDS transpose -> 8 rows x 128B full-line NT stores ----
        const int i0 = iBase + fc * 16;
        const int ia = i0 + rrow, ic = i0 + 8 + rrow;
        float* outp[3] = {out, out + BNT, out + 2 * BNT};
        f32x4* vals[3][2] = {{&vmu[0], &vmu[1]}, {&vch[0], &vch[1]}, {&vel[0], &vel[1]}};
        #pragma unroll
        for (int ov = 0; ov < 3; ++ov) {
            *(f32x4*)&fb[lo * FBS + hi * 4]      = *vals[ov][0];
            *(f32x4*)&fb[lo * FBS + 16 + hi * 4] = *vals[ov][1];
            const f32x4 s0 = *(const f32x4*)&fb[rrow * FBS + rcol];
            const f32x4 s1 = *(const f32x4*)&fb[(8 + rrow) * FBS + rcol];
            if (ia < NN)
                __builtin_nontemporal_store(s0, (f32x4*)&outp[ov][bOff + (size_t)ia * TTOT + t0 + rcol]);
            if (ic < NN)
                __builtin_nontemporal_store(s1, (f32x4*)&outp[ov][bOff + (size_t)ic * TTOT + t0 + rcol]);
        }
    }
}

extern "C" void kernel_launch(void* const* d_in, const int* in_sizes, int n_in,
                              void* d_out, int out_size, void* d_ws, size_t ws_size,
                              hipStream_t stream) {
    const float* input  = (const float*)d_in[0];
    const float* hidden = (const float*)d_in[1];
    const float* sc     = (const float*)d_in[2];
    const float* se     = (const float*)d_in[3];
    const float* mc     = (const float*)d_in[4];
    const float* me     = (const float*)d_in[5];
    const float* E      = (const float*)d_in[6];
    const float* bias   = (const float*)d_in[7];
    const float* tau    = (const float*)d_in[8];
    float* out = (float*)d_out;

    ushort* WebP = (ushort*)d_ws;
    float*  scal = (float*)((char*)d_ws + OFF_SCAL);

    lic_prep<<<MPAD, 64, 0, stream>>>(sc, se, mc, me, E, bias, tau, WebP, scal);
    lic_fused<<<TB * NTC, 256, 0, stream>>>(input, hidden, WebP, scal, out);
}